// Round 1
// baseline (842.736 us; speedup 1.0000x reference)
//
#include <hip/hip_runtime.h>
#include <hip/hip_bf16.h>

#define BB 8
#define CINC 64
#define COUTC 64
#define HH 128
#define WW 128
#define NN 16384      // H*W
#define NHEADS 4
#define CRR 32

// ---------------------------------------------------------------------------
// k0: fold weights.
//   S[h][k] = sum_c att_src[h][c] * w_lin[(h*32+c)*32 + k]
//   D[h][k] = sum_c att_dst[h][c] * w_lin[(h*32+c)*32 + k]
//   rb[o]   = sum_c w_restore[o][c] * b_gat[c]
// ---------------------------------------------------------------------------
__global__ void gat_k0(const float* __restrict__ w_lin,
                       const float* __restrict__ att_src,
                       const float* __restrict__ att_dst,
                       const float* __restrict__ w_restore,
                       const float* __restrict__ b_gat,
                       float* __restrict__ S, float* __restrict__ D,
                       float* __restrict__ rb) {
    int t = threadIdx.x;
    if (t < 128) {
        int h = t >> 5, k = t & 31;
        float s = 0.f, d = 0.f;
        for (int c = 0; c < 32; ++c) {
            float wl = w_lin[(h * 32 + c) * 32 + k];
            s += att_src[h * 32 + c] * wl;
            d += att_dst[h * 32 + c] * wl;
        }
        S[t] = s; D[t] = d;
    } else if (t < 192) {
        int o = t - 128;
        float r = 0.f;
        for (int c = 0; c < 32; ++c) r += w_restore[o * 32 + c] * b_gat[c];
        rb[o] = r;
    }
}

// ---------------------------------------------------------------------------
// k1: reduced features + attention logits.
//   red[b][k][v] = sum_cin w_reduce[k][cin] * x[b][cin][v]
//   a_s[b][h][v] = S[h] . red[b][:,v],  a_d likewise
// one thread per node. 512 blocks x 256.
// ---------------------------------------------------------------------------
__global__ __launch_bounds__(256) void gat_k1(
        const float* __restrict__ x, const float* __restrict__ w_reduce,
        const float* __restrict__ S, const float* __restrict__ D,
        float* __restrict__ red_ws, float* __restrict__ as_ws,
        float* __restrict__ ad_ws) {
    __shared__ float wred[32 * 64];
    __shared__ float Sl[128];
    __shared__ float Dl[128];
    int tid = threadIdx.x;
    for (int t = tid; t < 2048; t += 256) wred[t] = w_reduce[t];
    if (tid < 128) Sl[tid] = S[tid];
    else           Dl[tid - 128] = D[tid - 128];
    __syncthreads();

    int gid = blockIdx.x * 256 + tid;
    int b = gid >> 14;
    int v = gid & (NN - 1);

    const float* xb = x + ((size_t)b * CINC) * NN + v;
    float xv[64];
#pragma unroll
    for (int c = 0; c < 64; ++c) xv[c] = xb[(size_t)c * NN];

    float red[32];
#pragma unroll
    for (int k = 0; k < 32; ++k) {
        const float4* w4 = reinterpret_cast<const float4*>(&wred[k * 64]);
        float acc = 0.f;
#pragma unroll
        for (int c4 = 0; c4 < 16; ++c4) {
            float4 w = w4[c4];
            acc += w.x * xv[4 * c4] + w.y * xv[4 * c4 + 1] +
                   w.z * xv[4 * c4 + 2] + w.w * xv[4 * c4 + 3];
        }
        red[k] = acc;
    }

    float* rp = red_ws + ((size_t)b * 32) * NN + v;
#pragma unroll
    for (int k = 0; k < 32; ++k) rp[(size_t)k * NN] = red[k];

#pragma unroll
    for (int h = 0; h < 4; ++h) {
        const float4* s4 = reinterpret_cast<const float4*>(&Sl[h * 32]);
        const float4* d4 = reinterpret_cast<const float4*>(&Dl[h * 32]);
        float as = 0.f, ad = 0.f;
#pragma unroll
        for (int k4 = 0; k4 < 8; ++k4) {
            float4 sv = s4[k4], dv = d4[k4];
            as += sv.x * red[4 * k4] + sv.y * red[4 * k4 + 1] +
                  sv.z * red[4 * k4 + 2] + sv.w * red[4 * k4 + 3];
            ad += dv.x * red[4 * k4] + dv.y * red[4 * k4 + 1] +
                  dv.z * red[4 * k4 + 2] + dv.w * red[4 * k4 + 3];
        }
        as_ws[((size_t)b * 4 + h) * NN + v] = as;
        ad_ws[((size_t)b * 4 + h) * NN + v] = ad;
    }
}

// ---------------------------------------------------------------------------
// k2: stencil softmax + reduced-space aggregation + head-mix + restore +
//     residual; writes pre-BN out into d_out; accumulates BN sum/sumsq.
// one thread per node in phase 1; channel-per-wave mapping in phase 2.
// 512 blocks x 256 (block = 256 consecutive nodes = 2 image rows).
// ---------------------------------------------------------------------------
__global__ __launch_bounds__(256, 2) void gat_k2(
        const float* __restrict__ x, const float* __restrict__ w_lin,
        const float* __restrict__ w_restore, const float* __restrict__ rb,
        const float* __restrict__ red_ws, const float* __restrict__ as_ws,
        const float* __restrict__ ad_ws, float* __restrict__ outp,
        float* __restrict__ stats) {
    __shared__ float wlin_lds[128 * 32];
    __shared__ float wres_lds[64 * 32];
    __shared__ float rb_lds[64];
    __shared__ float g_tile[32][256];

    int tid = threadIdx.x;
    for (int t = tid; t < 4096; t += 256) wlin_lds[t] = w_lin[t];
    for (int t = tid; t < 2048; t += 256) wres_lds[t] = w_restore[t];
    if (tid < 64) rb_lds[tid] = rb[tid];
    __syncthreads();

    int base = blockIdx.x * 256;
    int b = base >> 14;
    int v0 = base & (NN - 1);
    int v = v0 + tid;
    int i = v >> 7, j = v & 127;

    // ---- phase 1: attention + aggregation + head-mix ----
    float ad[4];
    const float* adp = ad_ws + (size_t)b * 4 * NN + v;
#pragma unroll
    for (int h = 0; h < 4; ++h) ad[h] = adp[(size_t)h * NN];

    bool nu = i > 0, ndn = i < 127, nl = j > 0, nr = j < 127;
    int un[5] = { v, nu ? v - 128 : v, ndn ? v + 128 : v,
                  nl ? v - 1 : v, nr ? v + 1 : v };
    float msk[5] = { 0.f, nu ? 0.f : -1e30f, ndn ? 0.f : -1e30f,
                     nl ? 0.f : -1e30f, nr ? 0.f : -1e30f };

    float al[5][4];
    const float* asp = as_ws + (size_t)b * 4 * NN;
#pragma unroll
    for (int n = 0; n < 5; ++n) {
#pragma unroll
        for (int h = 0; h < 4; ++h) {
            float e = asp[(size_t)h * NN + un[n]] + ad[h];
            e = e > 0.f ? e : 0.2f * e;          // leaky_relu(0.2)
            al[n][h] = e + msk[n];
        }
    }
#pragma unroll
    for (int h = 0; h < 4; ++h) {
        float m = al[0][h];
#pragma unroll
        for (int n = 1; n < 5; ++n) m = fmaxf(m, al[n][h]);
        float den = 0.f;
#pragma unroll
        for (int n = 0; n < 5; ++n) {
            float ex = __expf(al[n][h] - m);
            al[n][h] = ex; den += ex;
        }
        float inv = 1.f / den;
#pragma unroll
        for (int n = 0; n < 5; ++n) al[n][h] *= inv;
    }

    float racc[4][32];
#pragma unroll
    for (int h = 0; h < 4; ++h)
#pragma unroll
        for (int k = 0; k < 32; ++k) racc[h][k] = 0.f;

    const float* rp = red_ws + (size_t)b * 32 * NN;
#pragma unroll
    for (int n = 0; n < 5; ++n) {
        float a0 = al[n][0], a1 = al[n][1], a2 = al[n][2], a3 = al[n][3];
        const float* rpn = rp + un[n];
#pragma unroll
        for (int k = 0; k < 32; ++k) {
            float r = rpn[(size_t)k * NN];
            racc[0][k] += a0 * r; racc[1][k] += a1 * r;
            racc[2][k] += a2 * r; racc[3][k] += a3 * r;
        }
    }

    // g[c] = 0.25 * sum_h sum_k wlin[(h*32+c)][k] * racc[h][k]
#pragma unroll
    for (int c = 0; c < 32; ++c) {
        float acc = 0.f;
#pragma unroll
        for (int h = 0; h < 4; ++h) {
            const float4* w4 =
                reinterpret_cast<const float4*>(&wlin_lds[(h * 32 + c) * 32]);
#pragma unroll
            for (int k4 = 0; k4 < 8; ++k4) {
                float4 w = w4[k4];
                acc += w.x * racc[h][4 * k4] + w.y * racc[h][4 * k4 + 1] +
                       w.z * racc[h][4 * k4 + 2] + w.w * racc[h][4 * k4 + 3];
            }
        }
        g_tile[c][tid] = 0.25f * acc;
    }
    __syncthreads();

    // ---- phase 2: restore conv + residual + BN partial sums ----
    int wv = tid >> 6, lane = tid & 63;
    float s1[16], s2[16];
#pragma unroll
    for (int o = 0; o < 16; ++o) { s1[o] = 0.f; s2[o] = 0.f; }

    const float* xb = x + (size_t)b * CINC * NN;
    float* ob = outp + (size_t)b * COUTC * NN;
#pragma unroll
    for (int grp = 0; grp < 4; ++grp) {
        int nd = grp * 64 + lane;
        int vg = v0 + nd;
        float gv[32];
#pragma unroll
        for (int c = 0; c < 32; ++c) gv[c] = g_tile[c][nd];
#pragma unroll
        for (int o = 0; o < 16; ++o) {
            int och = wv * 16 + o;
            float acc = rb_lds[och];
            const float4* w4 =
                reinterpret_cast<const float4*>(&wres_lds[och * 32]);
#pragma unroll
            for (int c4 = 0; c4 < 8; ++c4) {
                float4 w = w4[c4];
                acc += w.x * gv[4 * c4] + w.y * gv[4 * c4 + 1] +
                       w.z * gv[4 * c4 + 2] + w.w * gv[4 * c4 + 3];
            }
            acc += xb[(size_t)och * NN + vg];      // residual
            ob[(size_t)och * NN + vg] = acc;
            s1[o] += acc; s2[o] += acc * acc;
        }
    }

#pragma unroll
    for (int o = 0; o < 16; ++o) {
        float r1 = s1[o], r2 = s2[o];
        for (int off = 32; off > 0; off >>= 1) {
            r1 += __shfl_xor(r1, off, 64);
            r2 += __shfl_xor(r2, off, 64);
        }
        if (lane == 0) {
            int och = wv * 16 + o;
            atomicAdd(&stats[och], r1);
            atomicAdd(&stats[64 + och], r2);
        }
    }
}

// ---------------------------------------------------------------------------
// k3: BN (batch stats) + ReLU, in place on d_out. float4 per thread.
// ---------------------------------------------------------------------------
__global__ __launch_bounds__(256) void gat_k3(
        float* __restrict__ out, const float* __restrict__ stats,
        const float* __restrict__ gamma, const float* __restrict__ beta) {
    int f = blockIdx.x * 256 + threadIdx.x;
    int e = f * 4;
    int c = (e >> 14) & 63;
    const float cnt_inv = 1.f / 131072.f;   // B*H*W
    float mean = stats[c] * cnt_inv;
    float var = stats[64 + c] * cnt_inv - mean * mean;
    float inv = rsqrtf(var + 1e-5f);
    float sc = gamma[c] * inv;
    float sh = beta[c] - mean * sc;
    float4 vv = reinterpret_cast<float4*>(out)[f];
    vv.x = fmaxf(vv.x * sc + sh, 0.f);
    vv.y = fmaxf(vv.y * sc + sh, 0.f);
    vv.z = fmaxf(vv.z * sc + sh, 0.f);
    vv.w = fmaxf(vv.w * sc + sh, 0.f);
    reinterpret_cast<float4*>(out)[f] = vv;
}

// ---------------------------------------------------------------------------
extern "C" void kernel_launch(void* const* d_in, const int* in_sizes, int n_in,
                              void* d_out, int out_size, void* d_ws, size_t ws_size,
                              hipStream_t stream) {
    const float* x         = (const float*)d_in[0];
    const float* w_reduce  = (const float*)d_in[1];
    const float* w_lin     = (const float*)d_in[2];
    const float* att_src   = (const float*)d_in[3];
    const float* att_dst   = (const float*)d_in[4];
    const float* b_gat     = (const float*)d_in[5];
    const float* w_restore = (const float*)d_in[6];
    const float* bn_gamma  = (const float*)d_in[7];
    const float* bn_beta   = (const float*)d_in[8];
    // src/dst (d_in[9], d_in[10]) unused: the grid structure is known.

    float* ws     = (float*)d_ws;
    float* red_ws = ws;                       // 8*32*16384 = 4,194,304
    float* as_ws  = red_ws + 4194304;         // 8*4*16384  =   524,288
    float* ad_ws  = as_ws + 524288;           //               524,288
    float* Sf     = ad_ws + 524288;           // 128
    float* Df     = Sf + 128;                 // 128
    float* rbf    = Df + 128;                 // 64
    float* stats  = rbf + 64;                 // 128 (sum[64], sumsq[64])

    hipMemsetAsync(stats, 0, 128 * sizeof(float), stream);

    gat_k0<<<1, 256, 0, stream>>>(w_lin, att_src, att_dst, w_restore, b_gat,
                                  Sf, Df, rbf);
    gat_k1<<<512, 256, 0, stream>>>(x, w_reduce, Sf, Df, red_ws, as_ws, ad_ws);
    gat_k2<<<512, 256, 0, stream>>>(x, w_lin, w_restore, rbf, red_ws, as_ws,
                                    ad_ws, (float*)d_out, stats);
    gat_k3<<<8192, 256, 0, stream>>>((float*)d_out, stats, bn_gamma, bn_beta);
}

// Round 2
// 805.971 us; speedup vs baseline: 1.0456x; 1.0456x over previous
//
#include <hip/hip_runtime.h>
#include <hip/hip_bf16.h>

#define BB 8
#define CINC 64
#define COUTC 64
#define HH 128
#define WW 128
#define NN 16384      // H*W
#define NHEADS 4
#define CRR 32

// ---------------------------------------------------------------------------
// k0: fold weights.
//   S[h][k] = sum_c att_src[h][c] * w_lin[(h*32+c)*32 + k]
//   D[h][k] = sum_c att_dst[h][c] * w_lin[(h*32+c)*32 + k]
//   rb[o]   = sum_c w_restore[o][c] * b_gat[c]
// ---------------------------------------------------------------------------
__global__ void gat_k0(const float* __restrict__ w_lin,
                       const float* __restrict__ att_src,
                       const float* __restrict__ att_dst,
                       const float* __restrict__ w_restore,
                       const float* __restrict__ b_gat,
                       float* __restrict__ S, float* __restrict__ D,
                       float* __restrict__ rb) {
    int t = threadIdx.x;
    if (t < 128) {
        int h = t >> 5, k = t & 31;
        float s = 0.f, d = 0.f;
        for (int c = 0; c < 32; ++c) {
            float wl = w_lin[(h * 32 + c) * 32 + k];
            s += att_src[h * 32 + c] * wl;
            d += att_dst[h * 32 + c] * wl;
        }
        S[t] = s; D[t] = d;
    } else if (t < 192) {
        int o = t - 128;
        float r = 0.f;
        for (int c = 0; c < 32; ++c) r += w_restore[o * 32 + c] * b_gat[c];
        rb[o] = r;
    }
}

// ---------------------------------------------------------------------------
// k1: reduced features + attention logits.
//   red[b][k][v] = sum_cin w_reduce[k][cin] * x[b][cin][v]
//   a_s[b][h][v] = S[h] . red[b][:,v],  a_d likewise
// one thread per node. 512 blocks x 256.
// ---------------------------------------------------------------------------
__global__ __launch_bounds__(256) void gat_k1(
        const float* __restrict__ x, const float* __restrict__ w_reduce,
        const float* __restrict__ S, const float* __restrict__ D,
        float* __restrict__ red_ws, float* __restrict__ as_ws,
        float* __restrict__ ad_ws) {
    __shared__ float wred[32 * 64];
    __shared__ float Sl[128];
    __shared__ float Dl[128];
    int tid = threadIdx.x;
    for (int t = tid; t < 2048; t += 256) wred[t] = w_reduce[t];
    if (tid < 128) Sl[tid] = S[tid];
    else           Dl[tid - 128] = D[tid - 128];
    __syncthreads();

    int gid = blockIdx.x * 256 + tid;
    int b = gid >> 14;
    int v = gid & (NN - 1);

    const float* xb = x + ((size_t)b * CINC) * NN + v;
    float xv[64];
#pragma unroll
    for (int c = 0; c < 64; ++c) xv[c] = xb[(size_t)c * NN];

    float red[32];
#pragma unroll
    for (int k = 0; k < 32; ++k) {
        const float4* w4 = reinterpret_cast<const float4*>(&wred[k * 64]);
        float acc = 0.f;
#pragma unroll
        for (int c4 = 0; c4 < 16; ++c4) {
            float4 w = w4[c4];
            acc += w.x * xv[4 * c4] + w.y * xv[4 * c4 + 1] +
                   w.z * xv[4 * c4 + 2] + w.w * xv[4 * c4 + 3];
        }
        red[k] = acc;
    }

    float* rp = red_ws + ((size_t)b * 32) * NN + v;
#pragma unroll
    for (int k = 0; k < 32; ++k) rp[(size_t)k * NN] = red[k];

#pragma unroll
    for (int h = 0; h < 4; ++h) {
        const float4* s4 = reinterpret_cast<const float4*>(&Sl[h * 32]);
        const float4* d4 = reinterpret_cast<const float4*>(&Dl[h * 32]);
        float as = 0.f, ad = 0.f;
#pragma unroll
        for (int k4 = 0; k4 < 8; ++k4) {
            float4 sv = s4[k4], dv = d4[k4];
            as += sv.x * red[4 * k4] + sv.y * red[4 * k4 + 1] +
                  sv.z * red[4 * k4 + 2] + sv.w * red[4 * k4 + 3];
            ad += dv.x * red[4 * k4] + dv.y * red[4 * k4 + 1] +
                  dv.z * red[4 * k4 + 2] + dv.w * red[4 * k4 + 3];
        }
        as_ws[((size_t)b * 4 + h) * NN + v] = as;
        ad_ws[((size_t)b * 4 + h) * NN + v] = ad;
    }
}

// ---------------------------------------------------------------------------
// k2: stencil softmax + reduced-space aggregation + head-mix + restore +
//     residual; writes pre-BN out into d_out; accumulates BN sum/sumsq.
// Heads processed in PAIRS (racc[2][32] live at once) to stay in registers
// -- round-1 version held racc[4][32]=128 accumulators and spilled to
//    scratch (762 MB WRITE_SIZE). 512 blocks x 256.
// ---------------------------------------------------------------------------
__global__ __launch_bounds__(256) void gat_k2(
        const float* __restrict__ x, const float* __restrict__ w_lin,
        const float* __restrict__ w_restore, const float* __restrict__ rb,
        const float* __restrict__ red_ws, const float* __restrict__ as_ws,
        const float* __restrict__ ad_ws, float* __restrict__ outp,
        float* __restrict__ stats) {
    __shared__ float wlin_lds[128 * 32];
    __shared__ float wres_lds[64 * 32];
    __shared__ float rb_lds[64];
    __shared__ float g_tile[32][256];

    int tid = threadIdx.x;
    for (int t = tid; t < 4096; t += 256) wlin_lds[t] = w_lin[t];
    for (int t = tid; t < 2048; t += 256) wres_lds[t] = w_restore[t];
    if (tid < 64) rb_lds[tid] = rb[tid];
    __syncthreads();

    int base = blockIdx.x * 256;
    int b = base >> 14;
    int v0 = base & (NN - 1);
    int v = v0 + tid;
    int i = v >> 7, j = v & 127;

    // ---- phase 1: attention weights ----
    float adv[4];
    const float* adp = ad_ws + (size_t)b * 4 * NN + v;
#pragma unroll
    for (int h = 0; h < 4; ++h) adv[h] = adp[(size_t)h * NN];

    bool nu = i > 0, ndn = i < 127, nl = j > 0, nr = j < 127;
    int un[5] = { v, nu ? v - 128 : v, ndn ? v + 128 : v,
                  nl ? v - 1 : v, nr ? v + 1 : v };
    float msk[5] = { 0.f, nu ? 0.f : -1e30f, ndn ? 0.f : -1e30f,
                     nl ? 0.f : -1e30f, nr ? 0.f : -1e30f };

    float al[5][4];
    const float* asp = as_ws + (size_t)b * 4 * NN;
#pragma unroll
    for (int n = 0; n < 5; ++n) {
#pragma unroll
        for (int h = 0; h < 4; ++h) {
            float e = asp[(size_t)h * NN + un[n]] + adv[h];
            e = e > 0.f ? e : 0.2f * e;          // leaky_relu(0.2)
            al[n][h] = e + msk[n];
        }
    }
#pragma unroll
    for (int h = 0; h < 4; ++h) {
        float m = al[0][h];
#pragma unroll
        for (int n = 1; n < 5; ++n) m = fmaxf(m, al[n][h]);
        float den = 0.f;
#pragma unroll
        for (int n = 0; n < 5; ++n) {
            float ex = __expf(al[n][h] - m);
            al[n][h] = ex; den += ex;
        }
        float inv = 1.f / den;
#pragma unroll
        for (int n = 0; n < 5; ++n) al[n][h] *= inv;
    }

    // ---- aggregation in reduced space, two heads at a time ----
    float g[32];
#pragma unroll
    for (int c = 0; c < 32; ++c) g[c] = 0.f;

    const float* rp = red_ws + (size_t)b * 32 * NN;
#pragma unroll
    for (int hp = 0; hp < 2; ++hp) {
        float racc0[32], racc1[32];
#pragma unroll
        for (int k = 0; k < 32; ++k) { racc0[k] = 0.f; racc1[k] = 0.f; }
#pragma unroll
        for (int n = 0; n < 5; ++n) {
            float a0 = al[n][2 * hp], a1 = al[n][2 * hp + 1];
            const float* rpn = rp + un[n];
#pragma unroll
            for (int k = 0; k < 32; ++k) {
                float r = rpn[(size_t)k * NN];
                racc0[k] += a0 * r; racc1[k] += a1 * r;
            }
        }
        // fold this head pair into g via w_lin (uniform LDS reads = broadcast)
#pragma unroll
        for (int c = 0; c < 32; ++c) {
            const float4* w0 = reinterpret_cast<const float4*>(
                &wlin_lds[((2 * hp) * 32 + c) * 32]);
            const float4* w1 = reinterpret_cast<const float4*>(
                &wlin_lds[((2 * hp + 1) * 32 + c) * 32]);
            float acc = 0.f;
#pragma unroll
            for (int k4 = 0; k4 < 8; ++k4) {
                float4 wa = w0[k4], wb = w1[k4];
                acc += wa.x * racc0[4 * k4]     + wa.y * racc0[4 * k4 + 1] +
                       wa.z * racc0[4 * k4 + 2] + wa.w * racc0[4 * k4 + 3] +
                       wb.x * racc1[4 * k4]     + wb.y * racc1[4 * k4 + 1] +
                       wb.z * racc1[4 * k4 + 2] + wb.w * racc1[4 * k4 + 3];
            }
            g[c] += acc;
        }
    }
#pragma unroll
    for (int c = 0; c < 32; ++c) g_tile[c][tid] = 0.25f * g[c];
    __syncthreads();

    // ---- phase 2: restore conv + residual + BN partial sums ----
    int wv = tid >> 6, lane = tid & 63;
    float s1[16], s2[16];
#pragma unroll
    for (int o = 0; o < 16; ++o) { s1[o] = 0.f; s2[o] = 0.f; }

    const float* xb = x + (size_t)b * CINC * NN;
    float* ob = outp + (size_t)b * COUTC * NN;
#pragma unroll
    for (int grp = 0; grp < 4; ++grp) {
        int nd = grp * 64 + lane;
        int vg = v0 + nd;
        float gv[32];
#pragma unroll
        for (int c = 0; c < 32; ++c) gv[c] = g_tile[c][nd];
#pragma unroll
        for (int o = 0; o < 16; ++o) {
            int och = wv * 16 + o;
            float acc = rb_lds[och];
            const float4* w4 =
                reinterpret_cast<const float4*>(&wres_lds[och * 32]);
#pragma unroll
            for (int c4 = 0; c4 < 8; ++c4) {
                float4 w = w4[c4];
                acc += w.x * gv[4 * c4] + w.y * gv[4 * c4 + 1] +
                       w.z * gv[4 * c4 + 2] + w.w * gv[4 * c4 + 3];
            }
            acc += xb[(size_t)och * NN + vg];      // residual
            ob[(size_t)och * NN + vg] = acc;
            s1[o] += acc; s2[o] += acc * acc;
        }
    }

#pragma unroll
    for (int o = 0; o < 16; ++o) {
        float r1 = s1[o], r2 = s2[o];
        for (int off = 32; off > 0; off >>= 1) {
            r1 += __shfl_xor(r1, off, 64);
            r2 += __shfl_xor(r2, off, 64);
        }
        if (lane == 0) {
            int och = wv * 16 + o;
            atomicAdd(&stats[och], r1);
            atomicAdd(&stats[64 + och], r2);
        }
    }
}

// ---------------------------------------------------------------------------
// k3: BN (batch stats) + ReLU, in place on d_out. float4 per thread.
// ---------------------------------------------------------------------------
__global__ __launch_bounds__(256) void gat_k3(
        float* __restrict__ out, const float* __restrict__ stats,
        const float* __restrict__ gamma, const float* __restrict__ beta) {
    int f = blockIdx.x * 256 + threadIdx.x;
    int e = f * 4;
    int c = (e >> 14) & 63;
    const float cnt_inv = 1.f / 131072.f;   // B*H*W
    float mean = stats[c] * cnt_inv;
    float var = stats[64 + c] * cnt_inv - mean * mean;
    float inv = rsqrtf(var + 1e-5f);
    float sc = gamma[c] * inv;
    float sh = beta[c] - mean * sc;
    float4 vv = reinterpret_cast<float4*>(out)[f];
    vv.x = fmaxf(vv.x * sc + sh, 0.f);
    vv.y = fmaxf(vv.y * sc + sh, 0.f);
    vv.z = fmaxf(vv.z * sc + sh, 0.f);
    vv.w = fmaxf(vv.w * sc + sh, 0.f);
    reinterpret_cast<float4*>(out)[f] = vv;
}

// ---------------------------------------------------------------------------
extern "C" void kernel_launch(void* const* d_in, const int* in_sizes, int n_in,
                              void* d_out, int out_size, void* d_ws, size_t ws_size,
                              hipStream_t stream) {
    const float* x         = (const float*)d_in[0];
    const float* w_reduce  = (const float*)d_in[1];
    const float* w_lin     = (const float*)d_in[2];
    const float* att_src   = (const float*)d_in[3];
    const float* att_dst   = (const float*)d_in[4];
    const float* b_gat     = (const float*)d_in[5];
    const float* w_restore = (const float*)d_in[6];
    const float* bn_gamma  = (const float*)d_in[7];
    const float* bn_beta   = (const float*)d_in[8];
    // src/dst (d_in[9], d_in[10]) unused: the grid structure is known.

    float* ws     = (float*)d_ws;
    float* red_ws = ws;                       // 8*32*16384 = 4,194,304
    float* as_ws  = red_ws + 4194304;         // 8*4*16384  =   524,288
    float* ad_ws  = as_ws + 524288;           //               524,288
    float* Sf     = ad_ws + 524288;           // 128
    float* Df     = Sf + 128;                 // 128
    float* rbf    = Df + 128;                 // 64
    float* stats  = rbf + 64;                 // 128 (sum[64], sumsq[64])

    hipMemsetAsync(stats, 0, 128 * sizeof(float), stream);

    gat_k0<<<1, 256, 0, stream>>>(w_lin, att_src, att_dst, w_restore, b_gat,
                                  Sf, Df, rbf);
    gat_k1<<<512, 256, 0, stream>>>(x, w_reduce, Sf, Df, red_ws, as_ws, ad_ws);
    gat_k2<<<512, 256, 0, stream>>>(x, w_lin, w_restore, rbf, red_ws, as_ws,
                                    ad_ws, (float*)d_out, stats);
    gat_k3<<<8192, 256, 0, stream>>>((float*)d_out, stats, bn_gamma, bn_beta);
}